// Round 7
// baseline (608.600 us; speedup 1.0000x reference)
//
#include <hip/hip_runtime.h>
#include <math.h>

#define LN2F 0.69314718055994531f

typedef _Float16 v8hf __attribute__((ext_vector_type(8)));
typedef float    v4f  __attribute__((ext_vector_type(4)));

// fast shifted-softplus via v_exp_f32/v_log_f32 (~10 VALU instr vs ~50 libm).
__device__ __forceinline__ float ssp_fast(float x) {
    float e = __expf(-fabsf(x));
    return fmaxf(x, 0.f) + __logf(1.f + e) - LN2F;
}

// ---------------------------------------------------------------------------
// Prep: weights -> f16, MFMA-B-fragment order.
// ---------------------------------------------------------------------------
__global__ __launch_bounds__(256)
void prep_kernel(const float* __restrict__ w1, const float* __restrict__ w2,
                 const float* __restrict__ l1w, const float* __restrict__ l2w,
                 const float* __restrict__ lw,
                 _Float16* __restrict__ w1f, _Float16* __restrict__ w2f,
                 _Float16* __restrict__ l1f, _Float16* __restrict__ l2f,
                 _Float16* __restrict__ lwf)
{
    int idx = blockIdx.x * 256 + threadIdx.x;
    if (idx < 8192) {  // w1f
        int i = idx & 7, lane = (idx >> 3) & 63, ks = (idx >> 9) & 1, nt = idx >> 10;
        int r = nt * 16 + (lane & 15);
        int k = ks * 32 + (lane >> 4) * 8 + i;
        w1f[idx] = (k < 50) ? (_Float16)w1[r * 50 + k] : (_Float16)0.f;
        return;
    }
    int o = idx - 8192;
    if (o >= 4 * 16384) return;
    int which = o >> 14;
    int p = o & 16383;
    int i = p & 7, lane = (p >> 3) & 63, ks = (p >> 9) & 3, nt = p >> 11;
    int r = nt * 16 + (lane & 15);
    int k = ks * 32 + (lane >> 4) * 8 + i;
    const float* src = (which == 0) ? w2 : (which == 1) ? l1w : (which == 2) ? l2w : lw;
    _Float16* dst   = (which == 0) ? w2f : (which == 1) ? l1f : (which == 2) ? l2f : lwf;
    dst[p] = (_Float16)src[r * 128 + k];
}

// ---------------------------------------------------------------------------
// h = X @ W^T (no bias/act). Column-split across blockIdx.y (4-way) for
// 2500 blocks -> latency amortized.
// ---------------------------------------------------------------------------
__global__ __launch_bounds__(256)
void h_gemm_kernel(const float* __restrict__ X, const _Float16* __restrict__ Wf,
                   float* __restrict__ Y, int M)
{
    const int tid = threadIdx.x, lane = tid & 63, wv = tid >> 6;
    const int l15 = lane & 15, quad = lane >> 4;
    const int mb = blockIdx.x * 64 + wv * 16;
    const int nt0 = blockIdx.y * 2;

    const int mA = (mb + l15 < M) ? (mb + l15) : (M - 1);
    v8hf a[4];
    #pragma unroll
    for (int ks = 0; ks < 4; ++ks) {
        const float4* xp = (const float4*)&X[(size_t)mA * 128 + ks * 32 + quad * 8];
        float4 x0 = xp[0], x1 = xp[1];
        v8hf t = {(_Float16)x0.x, (_Float16)x0.y, (_Float16)x0.z, (_Float16)x0.w,
                  (_Float16)x1.x, (_Float16)x1.y, (_Float16)x1.z, (_Float16)x1.w};
        a[ks] = t;
    }
    #pragma unroll
    for (int nt = nt0; nt < nt0 + 2; ++nt) {
        v4f acc = {0.f, 0.f, 0.f, 0.f};
        #pragma unroll
        for (int ks = 0; ks < 4; ++ks) {
            const v8hf b = *(const v8hf*)&Wf[((nt * 4 + ks) * 64 + lane) * 8];
            acc = __builtin_amdgcn_mfma_f32_16x16x32_f16(a[ks], b, acc, 0, 0, 0);
        }
        const int col = nt * 16 + l15;
        #pragma unroll
        for (int r = 0; r < 4; ++r) {
            int row = mb + quad * 4 + r;
            if (row < M) Y[(size_t)row * 128 + col] = acc[r];
        }
    }
}

// ---------------------------------------------------------------------------
// Fused tail: out = ssp(agg @ l2^T + l2b) @ lw^T + lb.
// Stage-2 column-split across blockIdx.y (stage-1 recomputed, MFMA is cheap).
// ---------------------------------------------------------------------------
__global__ __launch_bounds__(256)
void fused_out_kernel(const float* __restrict__ agg, const _Float16* __restrict__ l2f,
                      const float* __restrict__ l2b, const _Float16* __restrict__ lwf,
                      const float* __restrict__ lb, float* __restrict__ out, int M)
{
    __shared__ __align__(16) _Float16 Sh[64 * 138];
    const int tid = threadIdx.x, lane = tid & 63, wv = tid >> 6;
    const int l15 = lane & 15, quad = lane >> 4;
    const int m0 = wv * 16;
    const int gbase = blockIdx.x * 64;
    const int nt0 = blockIdx.y * 4;

    const int mA = (gbase + m0 + l15 < M) ? (gbase + m0 + l15) : (M - 1);
    v8hf a[4];
    #pragma unroll
    for (int ks = 0; ks < 4; ++ks) {
        const float4* xp = (const float4*)&agg[(size_t)mA * 128 + ks * 32 + quad * 8];
        float4 x0 = xp[0], x1 = xp[1];
        v8hf t = {(_Float16)x0.x, (_Float16)x0.y, (_Float16)x0.z, (_Float16)x0.w,
                  (_Float16)x1.x, (_Float16)x1.y, (_Float16)x1.z, (_Float16)x1.w};
        a[ks] = t;
    }
    #pragma unroll
    for (int nt = 0; nt < 8; ++nt) {
        v4f acc = {0.f, 0.f, 0.f, 0.f};
        #pragma unroll
        for (int ks = 0; ks < 4; ++ks) {
            const v8hf b = *(const v8hf*)&l2f[((nt * 4 + ks) * 64 + lane) * 8];
            acc = __builtin_amdgcn_mfma_f32_16x16x32_f16(a[ks], b, acc, 0, 0, 0);
        }
        const float bj = l2b[nt * 16 + l15];
        #pragma unroll
        for (int r = 0; r < 4; ++r)
            Sh[(m0 + quad * 4 + r) * 138 + nt * 16 + l15] =
                (_Float16)ssp_fast(acc[r] + bj);
    }
    v8hf ua[4];
    #pragma unroll
    for (int ks = 0; ks < 4; ++ks)
        ua[ks] = *(const v8hf*)&Sh[(m0 + l15) * 138 + ks * 32 + quad * 8];

    #pragma unroll
    for (int nt = nt0; nt < nt0 + 4; ++nt) {
        v4f acc = {0.f, 0.f, 0.f, 0.f};
        #pragma unroll
        for (int ks = 0; ks < 4; ++ks) {
            const v8hf b = *(const v8hf*)&lwf[((nt * 4 + ks) * 64 + lane) * 8];
            acc = __builtin_amdgcn_mfma_f32_16x16x32_f16(ua[ks], b, acc, 0, 0, 0);
        }
        const int col = nt * 16 + l15;
        const float bj = lb[col];
        #pragma unroll
        for (int r = 0; r < 4; ++r) {
            int row = gbase + m0 + quad * 4 + r;
            if (row < M) out[(size_t)row * 128 + col] = acc[r] + bj;
        }
    }
}

// ---------------------------------------------------------------------------
// dst-CSR: rank from histogram atomic return; two-level scan.
// ---------------------------------------------------------------------------
__global__ __launch_bounds__(256)
void rank_hist_kernel(const int* __restrict__ dst, int* __restrict__ cnt,
                      int* __restrict__ rank, int E)
{
    int i = blockIdx.x * 256 + threadIdx.x;
    const int stride = gridDim.x * 256;
    for (; i < E; i += stride) rank[i] = atomicAdd(&cnt[dst[i]], 1);
}

__global__ __launch_bounds__(256)
void scan1_kernel(int* __restrict__ data, int* __restrict__ bsum, int N)
{
    __shared__ int wsum[4];
    const int t = threadIdx.x, lane = t & 63, wv = t >> 6;
    const int base = blockIdx.x * 1024 + t * 4;
    int v0 = 0, v1 = 0, v2 = 0, v3 = 0;
    if (base + 0 < N) v0 = data[base + 0];
    if (base + 1 < N) v1 = data[base + 1];
    if (base + 2 < N) v2 = data[base + 2];
    if (base + 3 < N) v3 = data[base + 3];
    const int s = v0 + v1 + v2 + v3;
    int sc = s;
    #pragma unroll
    for (int d = 1; d < 64; d <<= 1) {
        int o = __shfl_up(sc, d);
        if (lane >= d) sc += o;
    }
    if (lane == 63) wsum[wv] = sc;
    __syncthreads();
    int wo = 0;
    for (int j = 0; j < wv; ++j) wo += wsum[j];
    int run = wo + (sc - s);
    if (base + 0 < N) data[base + 0] = run; run += v0;
    if (base + 1 < N) data[base + 1] = run; run += v1;
    if (base + 2 < N) data[base + 2] = run; run += v2;
    if (base + 3 < N) data[base + 3] = run; run += v3;
    if (t == 255) bsum[blockIdx.x] = wo + sc;
}

__global__ __launch_bounds__(256)
void scan2_kernel(int* __restrict__ offs, const int* __restrict__ bsum, int N, int E)
{
    int add = 0;
    for (int j = 0; j < (int)blockIdx.x; ++j) add += bsum[j];
    const int base = blockIdx.x * 1024 + threadIdx.x * 4;
    #pragma unroll
    for (int r = 0; r < 4; ++r) {
        int i = base + r;
        if (i < N) offs[i] += add;
    }
    if (blockIdx.x == 0 && threadIdx.x == 0) offs[N] = E;
}

// ---------------------------------------------------------------------------
// Fused permute: ONE pass over edges writes BOTH the 16B record and the
// attr row (f32->f16, 64-padded) directly at the dst-sorted slot.
// 8 threads per edge (sub = idx&7): sub j converts cols 8j..8j+7 and stores
// 16B; sub 0 also writes the record. Reads are linear/coalesced; writes are
// random 128B-row scatters -- fire-and-forget, latency hidden.
// Replaces attr16 + build_rec (two passes) AND removes the eid indirection
// from the edge kernel (its attr read becomes fully linear).
// ---------------------------------------------------------------------------
__global__ __launch_bounds__(256)
void perm_kernel(const float* __restrict__ attr, const float* __restrict__ ew,
                 const int* __restrict__ src, const int* __restrict__ dst,
                 const int* __restrict__ rank, const int* __restrict__ offs,
                 int4* __restrict__ recP, _Float16* __restrict__ attrP, int E)
{
    int idx = blockIdx.x * 256 + threadIdx.x;
    const int stride = gridDim.x * 256;
    const int total = E * 8;
    for (; idx < total; idx += stride) {
        const int e = idx >> 3, sub = idx & 7;
        const int d = dst[e];
        const int slot = offs[d] + rank[e];
        const float* rp = attr + (size_t)e * 50 + sub * 8;
        v8hf t;
        #pragma unroll
        for (int j = 0; j < 8; ++j) {
            const int c = sub * 8 + j;
            t[j] = (c < 50) ? (_Float16)rp[j] : (_Float16)0.f;
        }
        *(v8hf*)&attrP[(size_t)slot * 64 + sub * 8] = t;
        if (sub == 0) {
            int4 rec;
            rec.x = src[e];
            rec.y = d;
            rec.z = __float_as_int(0.5f * (__cosf(ew[e] * 0.31415926535897932f) + 1.f));
            rec.w = 0;
            recP[slot] = rec;
        }
    }
}

// ---------------------------------------------------------------------------
// Edge kernel v7: dst-sorted slots, ALL regular streams linear.
//   - attrP read LINEARLY (slot order) -- no eid indirection (r6 FETCH 181MB
//     was the attrL gather; this removes it).
//   - recP {src,dst,cC} linear 16B records.
//   - h-gather random (LLC-resident) -- the known ~latency floor.
//   - run-merged atomics (r5).
//   - weights from L2 (r6 proved residency ~ occupancy tradeoff is a wash;
//     this keeps VGPR at ~40 and occupancy at the LDS cap).
//   - (256,8): LDS 17.9KB -> 8 blocks/CU, 100% of the 32-wave cap.
// ---------------------------------------------------------------------------
__global__ __launch_bounds__(256, 8)
void edge_kernel(const _Float16* __restrict__ attrP, // E x 64, slot order
                 const int4* __restrict__ recP,      // E slots, dst-sorted
                 const _Float16* __restrict__ w1f,
                 const _Float16* __restrict__ w2f,
                 const float* __restrict__ b1,
                 const float* __restrict__ b2,
                 const float* __restrict__ h,        // N x 128
                 float* __restrict__ agg,            // N x 128 (zeroed)
                 int E)
{
    __shared__ __align__(16) _Float16 Uh[64 * 138];

    const int tid = threadIdx.x;
    const int e_base = blockIdx.x * 64;
    const int lane = tid & 63, wv = tid >> 6;
    const int m0 = wv * 16, l15 = lane & 15, quad = lane >> 4;

    // ---- per-quad metadata from linear records ----
    const int s0 = e_base + m0 + quad * 4;
    int dIdx[4]; float cC[4]; const float* hrow[4]; float* arow[4]; bool val[4];
    #pragma unroll
    for (int r = 0; r < 4; ++r) {
        const int sg = s0 + r;
        val[r] = sg < E;
        const int s = val[r] ? sg : (E - 1);
        const int4 rec = recP[s];
        dIdx[r] = rec.y;
        cC[r] = __int_as_float(rec.z);
        hrow[r] = h + (size_t)rec.x * 128;
        arow[r] = agg + (size_t)rec.y * 128;
    }

    // ---- A-fragments: LINEAR slot rows ----
    int sA = e_base + m0 + l15;
    if (sA >= E) sA = E - 1;
    const _Float16* ap = attrP + (size_t)sA * 64;
    const v8hf a0 = *(const v8hf*)(ap + quad * 8);
    const v8hf a1 = *(const v8hf*)(ap + 32 + quad * 8);

    // ---- h-gather prefetch (random rows, LLC-resident) ----
    float hv[8][4];
    #pragma unroll
    for (int nt = 0; nt < 8; ++nt)
        #pragma unroll
        for (int r = 0; r < 4; ++r)
            hv[nt][r] = hrow[r][nt * 16 + l15];

    // ---- stage 1: u = ssp(attr @ W1^T + b1) -> Uh (wave-private rows) ----
    #pragma unroll
    for (int nt = 0; nt < 8; ++nt) {
        v4f acc = {0.f, 0.f, 0.f, 0.f};
        const v8hf bA = *(const v8hf*)&w1f[((nt * 2 + 0) * 64 + lane) * 8];
        const v8hf bB = *(const v8hf*)&w1f[((nt * 2 + 1) * 64 + lane) * 8];
        acc = __builtin_amdgcn_mfma_f32_16x16x32_f16(a0, bA, acc, 0, 0, 0);
        acc = __builtin_amdgcn_mfma_f32_16x16x32_f16(a1, bB, acc, 0, 0, 0);
        const float bj = b1[nt * 16 + l15];
        #pragma unroll
        for (int r = 0; r < 4; ++r)
            Uh[(m0 + quad * 4 + r) * 138 + nt * 16 + l15] =
                (_Float16)ssp_fast(acc[r] + bj);
    }

    // ---- stage 2 + run-merged atomic epilogue ----
    v8hf ua[4];
    #pragma unroll
    for (int ks = 0; ks < 4; ++ks)
        ua[ks] = *(const v8hf*)&Uh[(m0 + l15) * 138 + ks * 32 + quad * 8];

    #pragma unroll
    for (int nt = 0; nt < 8; ++nt) {
        v4f acc = {0.f, 0.f, 0.f, 0.f};
        #pragma unroll
        for (int ks = 0; ks < 4; ++ks) {
            const v8hf b = *(const v8hf*)&w2f[((nt * 4 + ks) * 64 + lane) * 8];
            acc = __builtin_amdgcn_mfma_f32_16x16x32_f16(ua[ks], b, acc, 0, 0, 0);
        }
        const int col = nt * 16 + l15;
        const float bj = b2[col];
        float m[4];
        #pragma unroll
        for (int r = 0; r < 4; ++r)
            m[r] = val[r] ? (acc[r] + bj) * cC[r] * hv[nt][r] : 0.f;
        float run = m[0];
        #pragma unroll
        for (int r = 1; r < 4; ++r) {
            if (dIdx[r] == dIdx[r - 1]) {
                run += m[r];
            } else {
                atomicAdd(arow[r - 1] + col, run);
                run = m[r];
            }
        }
        atomicAdd(arow[3] + col, run);
    }
}

extern "C" void kernel_launch(void* const* d_in, const int* in_sizes, int n_in,
                              void* d_out, int out_size, void* d_ws, size_t ws_size,
                              hipStream_t stream)
{
    const float* x   = (const float*)d_in[0];
    const int*   ei  = (const int*)  d_in[1];
    const float* ew  = (const float*)d_in[2];
    const float* ea  = (const float*)d_in[3];
    const float* w1  = (const float*)d_in[4];
    const float* b1  = (const float*)d_in[5];
    const float* w2  = (const float*)d_in[6];
    const float* b2  = (const float*)d_in[7];
    const float* l1w = (const float*)d_in[8];
    const float* l2w = (const float*)d_in[9];
    const float* l2b = (const float*)d_in[10];
    const float* lw  = (const float*)d_in[11];
    const float* lb  = (const float*)d_in[12];

    const int N = in_sizes[0] / 128;   // 40000
    const int E = in_sizes[2];         // 640000
    const int NB = (N + 1023) / 1024;

    char* base = (char*)d_ws;
    size_t off = 0;
    auto take = [&](size_t bytes) -> char* {
        char* r = base + off;
        off = (off + bytes + 255) & ~(size_t)255;
        return r;
    };
    float*    hbuf  = (float*)   take((size_t)N * 128 * 4);
    float*    agg   = (float*)   take((size_t)N * 128 * 4);
    _Float16* w1f   = (_Float16*)take(8192 * 2);
    _Float16* w2f   = (_Float16*)take(16384 * 2);
    _Float16* l1f   = (_Float16*)take(16384 * 2);
    _Float16* l2f   = (_Float16*)take(16384 * 2);
    _Float16* lwf   = (_Float16*)take(16384 * 2);
    int*      offs  = (int*)     take((size_t)(N + 1) * 4);
    int*      bsum  = (int*)     take((size_t)NB * 4);
    int*      rank  = (int*)     take((size_t)E * 4);
    int4*     recP  = (int4*)    take((size_t)E * 16);
    _Float16* attrP = (_Float16*)take((size_t)E * 64 * 2);

    const int nb = (N + 63) / 64;
    const int eb = (E + 63) / 64;
    const int tb = (E + 255) / 256;

    prep_kernel<<<288, 256, 0, stream>>>(w1, w2, l1w, l2w, lw,
                                         w1f, w2f, l1f, l2f, lwf);
    hipMemsetAsync(agg, 0, (size_t)N * 128 * sizeof(float), stream);
    hipMemsetAsync(offs, 0, (size_t)(N + 1) * sizeof(int), stream);

    rank_hist_kernel<<<tb, 256, 0, stream>>>(ei + E, offs, rank, E);
    scan1_kernel<<<NB, 256, 0, stream>>>(offs, bsum, N);
    scan2_kernel<<<NB, 256, 0, stream>>>(offs, bsum, N, E);
    perm_kernel<<<(E * 8 + 255) / 256, 256, 0, stream>>>(ea, ew, ei, ei + E,
                                                         rank, offs, recP, attrP, E);

    h_gemm_kernel<<<dim3(nb, 4), 256, 0, stream>>>(x, l1f, hbuf, N);
    edge_kernel<<<eb, 256, 0, stream>>>(attrP, recP, w1f, w2f, b1, b2,
                                        hbuf, agg, E);
    fused_out_kernel<<<dim3(nb, 2), 256, 0, stream>>>(agg, l2f, l2b, lwf, lb,
                                                      (float*)d_out, N);
}